// Round 1
// baseline (126.779 us; speedup 1.0000x reference)
//
#include <hip/hip_runtime.h>

#define A_ 8732
#define B_ 32
#define N_ 100
#define EPSF 1e-6f

// ---------------------------------------------------------------------------
// K1: per (b, a) — max/argmax IoU over the N ground-truth boxes.
// GT boxes for the batch staged in LDS (broadcast reads, conflict-free).
// Strict '>' with ascending n == numpy first-occurrence argmax.
// ---------------------------------------------------------------------------
__global__ __launch_bounds__(256) void k_best_per_anchor(
    const float* __restrict__ gt, const float* __restrict__ anchors,
    float* bg_iou, int* bg_idx) {
  int b = blockIdx.y;
  int a = blockIdx.x * 256 + threadIdx.x;
  __shared__ float s_gt[N_ * 4];
  const float* g = gt + (size_t)b * N_ * 4;
  for (int i = threadIdx.x; i < N_ * 4; i += 256) s_gt[i] = g[i];
  __syncthreads();
  if (a >= A_) return;

  float4 an = ((const float4*)anchors)[a];
  float ax0 = an.x - an.z * 0.5f, ay0 = an.y - an.w * 0.5f;
  float ax1 = an.x + an.z * 0.5f, ay1 = an.y + an.w * 0.5f;
  float area_a = (ax1 - ax0) * (ay1 - ay0);

  float best = -1.0f;
  int bi = 0;
  for (int n = 0; n < N_; n++) {
    float bx0 = s_gt[n * 4 + 0], by0 = s_gt[n * 4 + 1];
    float bx1 = s_gt[n * 4 + 2], by1 = s_gt[n * 4 + 3];
    float lx = fmaxf(ax0, bx0), ly = fmaxf(ay0, by0);
    float rx = fminf(ax1, bx1), ry = fminf(ay1, by1);
    float w = fmaxf(rx - lx, 0.0f), h = fmaxf(ry - ly, 0.0f);
    float inter = w * h;
    float area_b = (bx1 - bx0) * (by1 - by0);
    float uni = area_a + area_b - inter;
    float iou = inter / fmaxf(uni, EPSF);
    if (iou > best) { best = iou; bi = n; }
  }
  size_t idx = (size_t)b * A_ + a;
  bg_iou[idx] = best;
  bg_idx[idx] = bi;
}

// ---------------------------------------------------------------------------
// K2: per (b, n) — argmax IoU over the A anchors.
// Packed u64 key: (iou_bits << 32) | (0xFFFFFFFF - a).
// IoU >= +0.0 always, so float bits are monotone as unsigned; inverted index
// gives first-occurrence tie-breaking (numpy argmax semantics).
// ---------------------------------------------------------------------------
__global__ __launch_bounds__(256) void k_best_anchor(
    const float* __restrict__ gt, const float* __restrict__ anchors,
    int* __restrict__ best_anchor) {
  int bn = blockIdx.x;
  int b = bn / N_, n = bn - b * N_;
  const float* g = gt + (size_t)(b * N_ + n) * 4;
  float bx0 = g[0], by0 = g[1], bx1 = g[2], by1 = g[3];
  float area_b = (bx1 - bx0) * (by1 - by0);

  unsigned long long bestkey = 0ull;
  for (int a = threadIdx.x; a < A_; a += 256) {
    float4 an = ((const float4*)anchors)[a];
    float ax0 = an.x - an.z * 0.5f, ay0 = an.y - an.w * 0.5f;
    float ax1 = an.x + an.z * 0.5f, ay1 = an.y + an.w * 0.5f;
    float lx = fmaxf(ax0, bx0), ly = fmaxf(ay0, by0);
    float rx = fminf(ax1, bx1), ry = fminf(ay1, by1);
    float w = fmaxf(rx - lx, 0.0f), h = fmaxf(ry - ly, 0.0f);
    float inter = w * h;
    float area_a = (ax1 - ax0) * (ay1 - ay0);
    float uni = area_a + area_b - inter;
    float iou = inter / fmaxf(uni, EPSF);
    unsigned long long key =
        ((unsigned long long)__float_as_uint(iou) << 32) |
        (unsigned long long)(0xFFFFFFFFu - (unsigned)a);
    if (key > bestkey) bestkey = key;
  }

  __shared__ unsigned long long sred[256];
  sred[threadIdx.x] = bestkey;
  __syncthreads();
  for (int s = 128; s > 0; s >>= 1) {
    if (threadIdx.x < s) {
      unsigned long long o = sred[threadIdx.x + s];
      if (o > sred[threadIdx.x]) sred[threadIdx.x] = o;
    }
    __syncthreads();
  }
  if (threadIdx.x == 0) {
    best_anchor[bn] =
        (int)(0xFFFFFFFFu - (unsigned)(sred[0] & 0xFFFFFFFFull));
  }
}

// ---------------------------------------------------------------------------
// K3: per batch — serial ascending-n scatter (exact last-write-wins, matching
// index_put semantics), plus any_valid from mask bytes. 32 active lanes.
// Mask read as bytes is memory-safe whether bool landed as u8 or i32.
// ---------------------------------------------------------------------------
__global__ void k_scatter(const int* __restrict__ best_anchor,
                          const unsigned char* __restrict__ mask,
                          float* bg_iou, int* bg_idx,
                          int* __restrict__ any_valid) {
  int b = threadIdx.x;
  if (b >= B_) return;
  int any = 0;
  for (int j = 0; j < N_; j++) any |= mask[b * N_ + j];
  any_valid[b] = (any != 0) ? 1 : 0;
  for (int n = 0; n < N_; n++) {
    int a = best_anchor[b * N_ + n];
    bg_idx[(size_t)b * A_ + a] = n;
    bg_iou[(size_t)b * A_ + a] = 2.0f;
  }
}

// ---------------------------------------------------------------------------
// K4: per (b, a) — gather matched GT, encode, write all three outputs.
// bg_iou / bg_idx alias the label/mask regions of d_out; each thread reads its
// slots before overwriting them (no __restrict__ on aliased pointers).
// ---------------------------------------------------------------------------
__global__ __launch_bounds__(256) void k_finalize(
    const float* __restrict__ gt, const int* __restrict__ labels,
    const float* __restrict__ anchors, const int* __restrict__ any_valid,
    const float* bg_iou, const int* bg_idx, float* out) {
  const long long BA = (long long)B_ * A_;
  long long idx = (long long)blockIdx.x * 256 + threadIdx.x;
  if (idx >= BA) return;
  int b = (int)(idx / A_);
  int a = (int)(idx - (long long)b * A_);

  float iou = bg_iou[idx];
  int gi = bg_idx[idx];
  bool pos = iou > 0.5f;

  float4 an = ((const float4*)anchors)[a];
  const float* g = gt + (size_t)(b * N_ + gi) * 4;
  float gx = g[0], gy = g[1], gw = g[2], gh = g[3];

  float ex = (gx - an.x) / an.z;
  float ey = (gy - an.y) / an.w;
  float ew = logf((gw + EPSF) / (an.z + EPSF));
  float eh = logf((gh + EPSF) / (an.w + EPSF));
  int lab = pos ? labels[b * N_ + gi] : 0;

  if (!any_valid[b]) { ex = 0.0f; ey = 0.0f; ew = 0.0f; eh = 0.0f; lab = 0; }

  ((float4*)out)[idx] = make_float4(ex, ey, ew, eh);   // encoded [B,A,4]
  out[4 * BA + idx] = (float)lab;                      // labels  [B,A]
  out[5 * BA + idx] = pos ? 1.0f : 0.0f;               // pos_mask[B,A]
}

extern "C" void kernel_launch(void* const* d_in, const int* in_sizes, int n_in,
                              void* d_out, int out_size, void* d_ws,
                              size_t ws_size, hipStream_t stream) {
  const float* gt = (const float*)d_in[0];
  const int* labels = (const int*)d_in[1];
  const unsigned char* mask = (const unsigned char*)d_in[2];
  const float* anchors = (const float*)d_in[3];
  float* out = (float*)d_out;

  const size_t BA = (size_t)B_ * A_;
  // Scratch-in-output: label region holds best_gt_iou, mask region holds
  // best_gt_idx until K4 overwrites them (read-before-write per thread).
  float* bg_iou = out + 4 * BA;
  int* bg_idx = (int*)(out + 5 * BA);
  // Small scratch in ws (~13 KB).
  int* best_anchor = (int*)d_ws;            // B*N ints
  int* any_valid = best_anchor + B_ * N_;   // B ints

  dim3 g1((A_ + 255) / 256, B_);
  k_best_per_anchor<<<g1, 256, 0, stream>>>(gt, anchors, bg_iou, bg_idx);
  k_best_anchor<<<B_ * N_, 256, 0, stream>>>(gt, anchors, best_anchor);
  k_scatter<<<1, 64, 0, stream>>>(best_anchor, mask, bg_iou, bg_idx, any_valid);
  k_finalize<<<(int)((BA + 255) / 256), 256, 0, stream>>>(
      gt, labels, anchors, any_valid, bg_iou, bg_idx, out);
}

// Round 2
// 125.884 us; speedup vs baseline: 1.0071x; 1.0071x over previous
//
#include <hip/hip_runtime.h>

#define A_ 8732
#define B_ 32
#define N_ 100
#define NBLK 35  // ceil(A_/256)
#define EPSF 1e-6f

// ws layout:
//   partial[B_*N_*NBLK] u64  -- per-(b,n) per-block best keys (0..896000 B)
//   map[B_*A_] int           -- override n per anchor, -1 = none
//   any_valid[B_] int
// All ws regions are fully overwritten every launch (no init needed).

// ---------------------------------------------------------------------------
// K1: per (b, a) — per-anchor max/argmax over n (strict '>' ascending ==
// numpy first-occurrence), PLUS per-n wave-level max over anchors fused in.
// Key = (iou_bits << 32) | (0xFFFFFFFF - a): IoU >= +0 and never -0 (x-x=+0
// in RNE, so clipped w/h can't be -0), so float bits are monotone unsigned;
// inverted index gives global first-occurrence tie-breaking.
// ---------------------------------------------------------------------------
__global__ __launch_bounds__(256) void k_main(
    const float* __restrict__ gt, const float* __restrict__ anchors,
    float* __restrict__ bg_iou, int* __restrict__ bg_idx,
    unsigned long long* __restrict__ partial, int* __restrict__ map) {
  int b = blockIdx.y;
  int bx = blockIdx.x;
  int tid = threadIdx.x;
  int a = bx * 256 + tid;
  bool valid = a < A_;
  int aa = valid ? a : (A_ - 1);

  __shared__ float s_gt[N_ * 4];
  __shared__ unsigned long long s_part[4 * N_];
  const float* g = gt + (size_t)b * N_ * 4;
  for (int i = tid; i < N_ * 4; i += 256) s_gt[i] = g[i];
  __syncthreads();

  float4 an = ((const float4*)anchors)[aa];
  float ax0 = an.x - an.z * 0.5f, ay0 = an.y - an.w * 0.5f;
  float ax1 = an.x + an.z * 0.5f, ay1 = an.y + an.w * 0.5f;
  float area_a = (ax1 - ax0) * (ay1 - ay0);

  int wid = tid >> 6;
  int lane = tid & 63;
  int wave_a0 = bx * 256 + wid * 64;  // anchor of lane 0 of this wave

  float best = -1.0f;
  int bi = 0;
  for (int n = 0; n < N_; n++) {
    float bx0 = s_gt[n * 4 + 0], by0 = s_gt[n * 4 + 1];
    float bx1 = s_gt[n * 4 + 2], by1 = s_gt[n * 4 + 3];
    float lx = fmaxf(ax0, bx0), ly = fmaxf(ay0, by0);
    float rx = fminf(ax1, bx1), ry = fminf(ay1, by1);
    float w = fmaxf(rx - lx, 0.0f), h = fmaxf(ry - ly, 0.0f);
    float inter = w * h;
    float area_b = (bx1 - bx0) * (by1 - by0);
    float uni = area_a + area_b - inter;
    float iou = inter / fmaxf(uni, EPSF);

    // per-anchor running argmax (first occurrence)
    if (iou > best) { best = iou; bi = n; }

    // per-n wave max over the 64 anchors of this wave
    float r = valid ? iou : 0.0f;
    float m = r;
#pragma unroll
    for (int off = 32; off; off >>= 1) m = fmaxf(m, __shfl_xor(m, off, 64));
    unsigned long long winners = __ballot(r == m);
    int wl = __ffsll(winners) - 1;  // lowest lane == smallest anchor idx
    unsigned aw = (unsigned)(wave_a0 + wl);
    unsigned inva = (aw < A_) ? (0xFFFFFFFFu - aw) : 0u;
    if (lane == 0) {
      s_part[wid * N_ + n] =
          (((unsigned long long)__float_as_uint(m)) << 32) |
          (unsigned long long)inva;
    }
  }

  if (valid) {
    size_t idx = (size_t)b * A_ + a;
    bg_iou[idx] = best;
    bg_idx[idx] = bi;
    map[idx] = -1;  // init override map for K2's atomicMax
  }

  __syncthreads();
  for (int n = tid; n < N_; n += 256) {
    unsigned long long k = s_part[n];
    unsigned long long t;
    t = s_part[N_ + n];     if (t > k) k = t;
    t = s_part[2 * N_ + n]; if (t > k) k = t;
    t = s_part[3 * N_ + n]; if (t > k) k = t;
    partial[((size_t)b * N_ + n) * NBLK + bx] = k;
  }
}

// ---------------------------------------------------------------------------
// K2: per (b, n) — reduce 35 block partials -> winning anchor; last-write-
// wins scatter expressed as atomicMax over n (largest n == last write, exact
// index_put semantics). Also computes any_valid per batch.
// ---------------------------------------------------------------------------
__global__ __launch_bounds__(256) void k_combine(
    const unsigned long long* __restrict__ partial,
    const unsigned char* __restrict__ mask,
    int* __restrict__ map, int* __restrict__ any_valid) {
  int bn = blockIdx.x * 256 + threadIdx.x;
  if (bn >= B_ * N_) return;
  const unsigned long long* p = partial + (size_t)bn * NBLK;
  unsigned long long k = p[0];
  for (int i = 1; i < NBLK; i++) {
    unsigned long long t = p[i];
    if (t > k) k = t;
  }
  int b = bn / N_;
  int n = bn - b * N_;
  unsigned a_win = 0xFFFFFFFFu - (unsigned)(k & 0xFFFFFFFFull);
  atomicMax(&map[(size_t)b * A_ + a_win], n);
  if (n == 0) {
    int any = 0;
    for (int j = 0; j < N_; j++) any |= mask[b * N_ + j];
    any_valid[b] = any ? 1 : 0;
  }
}

// ---------------------------------------------------------------------------
// K3: per (b, a) — apply override map, gather matched GT, encode, write.
// bg_iou / bg_idx alias the label/mask regions of d_out; each thread reads
// its slots before overwriting them (no __restrict__ on aliased pointers).
// Math kept bit-identical to the R1-passing version.
// ---------------------------------------------------------------------------
__global__ __launch_bounds__(256) void k_finalize(
    const float* __restrict__ gt, const int* __restrict__ labels,
    const float* __restrict__ anchors, const int* __restrict__ any_valid,
    const int* __restrict__ map, const float* bg_iou, const int* bg_idx,
    float* out) {
  const long long BA = (long long)B_ * A_;
  long long idx = (long long)blockIdx.x * 256 + threadIdx.x;
  if (idx >= BA) return;
  int b = (int)(idx / A_);
  int a = (int)(idx - (long long)b * A_);

  float iou = bg_iou[idx];
  int gi = bg_idx[idx];
  int ov = map[idx];
  bool pos;
  if (ov >= 0) {
    gi = ov;
    pos = true;  // scattered best_gt_iou = 2.0 > 0.5
  } else {
    pos = iou > 0.5f;
  }

  float4 an = ((const float4*)anchors)[a];
  const float* g = gt + (size_t)(b * N_ + gi) * 4;
  float gx = g[0], gy = g[1], gw = g[2], gh = g[3];

  float ex = (gx - an.x) / an.z;
  float ey = (gy - an.y) / an.w;
  float ew = logf((gw + EPSF) / (an.z + EPSF));
  float eh = logf((gh + EPSF) / (an.w + EPSF));
  int lab = pos ? labels[b * N_ + gi] : 0;

  if (!any_valid[b]) { ex = 0.0f; ey = 0.0f; ew = 0.0f; eh = 0.0f; lab = 0; }

  ((float4*)out)[idx] = make_float4(ex, ey, ew, eh);  // encoded [B,A,4]
  out[4 * BA + idx] = (float)lab;                     // labels  [B,A]
  out[5 * BA + idx] = pos ? 1.0f : 0.0f;              // pos_mask[B,A]
}

extern "C" void kernel_launch(void* const* d_in, const int* in_sizes, int n_in,
                              void* d_out, int out_size, void* d_ws,
                              size_t ws_size, hipStream_t stream) {
  const float* gt = (const float*)d_in[0];
  const int* labels = (const int*)d_in[1];
  const unsigned char* mask = (const unsigned char*)d_in[2];
  const float* anchors = (const float*)d_in[3];
  float* out = (float*)d_out;

  const size_t BA = (size_t)B_ * A_;
  // Scratch-in-output: label region holds best_gt_iou, mask region holds
  // best_gt_idx until K3 overwrites them (read-before-write per thread).
  float* bg_iou = out + 4 * BA;
  int* bg_idx = (int*)(out + 5 * BA);

  // ws scratch
  unsigned long long* partial = (unsigned long long*)d_ws;  // B*N*NBLK u64
  int* map = (int*)(partial + (size_t)B_ * N_ * NBLK);      // B*A int
  int* any_valid = map + BA;                                // B int

  dim3 g1(NBLK, B_);
  k_main<<<g1, 256, 0, stream>>>(gt, anchors, bg_iou, bg_idx, partial, map);
  k_combine<<<(B_ * N_ + 255) / 256, 256, 0, stream>>>(partial, mask, map,
                                                       any_valid);
  k_finalize<<<(int)((BA + 255) / 256), 256, 0, stream>>>(
      gt, labels, anchors, any_valid, map, bg_iou, bg_idx, out);
}